// Round 5
// baseline (623.318 us; speedup 1.0000x reference)
//
#include <hip/hip_runtime.h>
#include <stdint.h>

#define V_ITEMS 100000
#define EDIM    128
#define BATCH   4096
#define HLEN    50
#define TOPK    21

#define MT      64                      // batches per block in K2
#define MS      4                       // 16-row MFMA sub-blocks (MT/16)
#define VSPLIT  4                       // item-range splits
#define NCHUNK_TOT (V_ITEMS / 16)       // 6250 16-item chunks total
#define NCH_MAX ((NCHUNK_TOT + VSPLIT - 1) / VSPLIT)   // 1563
#define NITER   ((NCH_MAX + 7) / 8)     // 196 iterations (8 waves) -- even
#define NKEEP   32                      // exact top-32 kept per (row, range)
#define SEGSZ   32                      // per-(row,wave) private segment
#define CAPR    (NKEEP + 8 * SEGSZ)     // 288 slots per row
#define NCAND   (NKEEP * VSPLIT)        // 128 candidates per batch into K3

typedef __attribute__((ext_vector_type(8))) short          bf16x8;
typedef __attribute__((ext_vector_type(4))) float          f32x4;
typedef __attribute__((ext_vector_type(8))) unsigned short u16x8;

__device__ inline unsigned short f2bf(float x) {           // RNE fp32->bf16
    unsigned u = __float_as_uint(x);
    return (unsigned short)((u + 0x7FFFu + ((u >> 16) & 1u)) >> 16);
}

// ---------------- K0: emb fp32 -> bf16 table in ws --------------------------
__global__ __launch_bounds__(256) void conv_bf16(
        const float* __restrict__ s, unsigned short* __restrict__ d) {
    size_t i = (size_t)blockIdx.x * 256 + threadIdx.x;     // 8 floats/thread
    const float4* sp = (const float4*)s + i * 2;
    float4 a = sp[0], b = sp[1];
    u16x8 o;
    o[0] = f2bf(a.x); o[1] = f2bf(a.y); o[2] = f2bf(a.z); o[3] = f2bf(a.w);
    o[4] = f2bf(b.x); o[5] = f2bf(b.y); o[6] = f2bf(b.z); o[7] = f2bf(b.w);
    *((u16x8*)d + i) = o;
}

// ---------------- K1: masked mean-pool queries -> bf16 ----------------------
__global__ __launch_bounds__(EDIM) void query_bf16(
        const int* __restrict__ seq, const int* __restrict__ len,
        const float* __restrict__ emb, unsigned short* __restrict__ qbf) {
    int b = blockIdx.x, d = threadIdx.x;
    int n = len[b];
    float s = 0.f;
    for (int l = 0; l < n; l++)
        s += emb[(size_t)seq[b * HLEN + l] * EDIM + d];
    qbf[b * EDIM + d] = f2bf(s / (float)(n > 0 ? n : 1));
}

// ---- exact top-32 of one row's {compacted zone + 8 segments}: bisection ----
// 288 slots -> 5 elements/lane. Validity: [0,32) vs ncomp; segments vs segcnt.
__device__ inline void compact_row(uint2* cb, const int* segcnt, int* ncomp,
                                   float* thr, int b, int lane) {
    int nc = ncomp[b];
    unsigned key[5]; unsigned vraw[5]; unsigned item[5];
    #pragma unroll
    for (int e = 0; e < 5; e++) {
        int i = lane + e * 64;                       // 0..319
        bool v;
        if (i < NKEEP)      v = (i < nc);
        else if (i < CAPR)  v = ((i - NKEEP) & (SEGSZ - 1)) <
                                segcnt[b * 8 + ((i - NKEEP) >> 5)];
        else                v = false;
        if (v) {
            uint2 d = cb[b * CAPR + i];
            unsigned u = d.x;
            key[e] = (u & 0x80000000u) ? ~u : (u | 0x80000000u);
            vraw[e] = u; item[e] = d.y;
        } else { key[e] = 0u; vraw[e] = 0u; item[e] = 0u; }
    }
    unsigned cur = 0u;                 // max T with count(key >= T) >= 32
    #pragma unroll 1
    for (int bit = 31; bit >= 0; bit--) {
        unsigned mid = cur | (1u << bit);
        int c = 0;
        #pragma unroll
        for (int e = 0; e < 5; e++)
            c += __popcll(__ballot(key[e] >= mid));
        if (c >= NKEEP) cur = mid;
    }
    int base = 0;                      // ballot prefix-sum compaction
    #pragma unroll
    for (int e = 0; e < 5; e++) {
        bool keep = key[e] >= cur;
        unsigned long long mm = __ballot(keep);
        int p = base + (int)__popcll(mm & ((1ull << lane) - 1ull));
        if (keep && p < NKEEP)
            cb[b * CAPR + p] = make_uint2(vraw[e], item[e]);
        base += (int)__popcll(mm);
    }
    if (lane == 0) {
        ncomp[b] = NKEEP;
        thr[b] = (cur & 0x80000000u) ? __uint_as_float(cur ^ 0x80000000u)
                                     : __uint_as_float(~cur);
    }
}

// ---------------- K2: bf16-MFMA scoring + fused per-range top-32 ------------
// grid = 64 batch-groups x 4 V-ranges = 256 blocks = 1/CU (LDS 150.5KB).
//
// R4 post-mortem: score-check throughput was INVARIANT (~0.025/cy/CU) across
// waves/SIMD 2/4/2 and 2x work/wave -> the limiter is the per-score insert
// path's serial overhead (16x {branch bubble + exec dance + dependent LDS
// atomic wait}), visible in no util counter. This version: per-(row,wave)
// private 32-slot segments; slot allocation by ballot+popc prefix in pure
// VALU; one unconditional ds_write_b64 per k (dump slot for failing lanes).
// ZERO branches / atomics / lgkm waits in the insert. Overflow per
// (row,wave,window) is Poisson(<=4.5) vs 32 slots (iter0 = exactly 16);
// pos<32 clamp makes the astronomical tail a benign drop. Compaction is
// unconditional at every event (no shared-capacity race class at all).
__global__ __launch_bounds__(512, 2) void score_topk(
        const unsigned short* __restrict__ qbf,
        const unsigned short* __restrict__ ebf,
        int* __restrict__ candOut) {
    __shared__ uint2 cb[MT * CAPR + 64];   // 144.5KB rows + dump
    __shared__ int   segcnt[MT * 8];       // 2KB
    __shared__ int   ncomp[MT];
    __shared__ float thr[MT];

    const int tid  = threadIdx.x;
    const int lane = tid & 63;
    const int w    = tid >> 6;                       // wave 0..7
    const int r    = blockIdx.x & (VSPLIT - 1);      // V-range
    const int mg   = blockIdx.x / VSPLIT;            // batch group
    const int b0   = mg * MT;
    const int n15  = lane & 15, quad = lane >> 4;
    const unsigned lm15 = (1u << n15) - 1u;
    const int dumpslot = MT * CAPR + lane;

    const int cstart = (r * NCHUNK_TOT) / VSPLIT;
    const int nch    = ((r + 1) * NCHUNK_TOT) / VSPLIT - cstart;  // 1562/1563

    if (tid < MT) { ncomp[tid] = 0; thr[tid] = -INFINITY; }
    __syncthreads();

    // resident A-fragments: 4 msubs x 4 K-steps (64 VGPRs)
    bf16x8 afr[MS][4];
    #pragma unroll
    for (int ms = 0; ms < MS; ms++)
        #pragma unroll
        for (int t = 0; t < 4; t++)
            afr[ms][t] = *(const bf16x8*)(qbf + (b0 + ms * 16 + n15) * EDIM
                                          + t * 32 + quad * 8);
    float thrR[16];
    int   curk[16];
    int   rowbase[16];
    #pragma unroll
    for (int k = 0; k < 16; k++) {
        thrR[k] = -INFINITY;
        curk[k] = 0;
        rowbase[k] = ((k >> 2) * 16 + (quad << 2) + (k & 3)) * CAPR
                     + NKEEP + w * SEGSZ;
    }

    const unsigned short* bbase = ebf + ((size_t)cstart * 16 + n15) * EDIM + quad * 8;

    int nextEvt = 1;

    // one iteration: MFMA+insert on `cur`, prefetch chunk(iter+1) into `nxt`
    auto body = [&](int iter, bf16x8 (&cur)[4], bf16x8 (&nxt)[4]) {
        {   // prefetch next iteration's B fragments
            int nit   = (iter + 1 < NITER) ? (iter + 1) : iter;
            int pch   = nit * 8 + w;
            int pcc   = (pch < nch) ? pch : (nch - 1);
            const unsigned short* bp = bbase + (size_t)pcc * (16 * EDIM);
            #pragma unroll
            for (int t = 0; t < 4; t++) nxt[t] = *(const bf16x8*)(bp + t * 32);
        }
        f32x4 acc[MS];
        #pragma unroll
        for (int ms = 0; ms < MS; ms++) acc[ms] = (f32x4){0.f, 0.f, 0.f, 0.f};
        #pragma unroll
        for (int t = 0; t < 4; t++)
            #pragma unroll
            for (int ms = 0; ms < MS; ms++)
                acc[ms] = __builtin_amdgcn_mfma_f32_16x16x32_bf16(afr[ms][t], cur[t], acc[ms], 0, 0, 0);

        int chunk = iter * 8 + w;
        bool act  = chunk < nch;                     // wave-uniform
        // C/D: item n = lane&15 (col), batch row = quad*4 + reg  [m89/m91]
        if (act) {
            unsigned item = (unsigned)((cstart + chunk) * 16 + n15);
            #pragma unroll
            for (int k = 0; k < 16; k++) {
                float sv = acc[k >> 2][k & 3];
                bool pass = sv > thrR[k];
                unsigned long long m = __ballot(pass);
                unsigned qm = (unsigned)((m >> (quad << 4)) & 0xFFFFull);
                int pos  = curk[k] + __popc(qm & lm15);
                int cnew = curk[k] + __popc(qm);
                curk[k] = cnew > SEGSZ ? SEGSZ : cnew;
                bool ok = pass && (pos < SEGSZ);
                int slot = ok ? (rowbase[k] + pos) : dumpslot;
                cb[slot] = make_uint2(__float_as_uint(sv), item);
            }
        }
        // static events: iters 1,2,4,...,128, and the final iter. Uniform
        // across waves. Unconditional compact of every row at every event.
        if (iter + 1 == nextEvt || iter + 1 == NITER) {
            if (iter + 1 == nextEvt) nextEvt <<= 1;
            if (n15 == 0) {                          // publish segment fills
                #pragma unroll
                for (int k = 0; k < 16; k++) {
                    int row = (k >> 2) * 16 + (quad << 2) + (k & 3);
                    segcnt[row * 8 + w] = curk[k];
                }
            }
            __syncthreads();
            #pragma unroll 1
            for (int j = 0; j < 8; j++)              // 8 rows per wave
                compact_row(cb, segcnt, ncomp, thr, (w << 3) + j, lane);
            __syncthreads();
            #pragma unroll
            for (int k = 0; k < 16; k++) {
                curk[k] = 0;
                thrR[k] = thr[(k >> 2) * 16 + (quad << 2) + (k & 3)];
            }
        }
    };

    bf16x8 bA[4], bB[4];
    {   // preload iter 0
        int cc0 = (w < nch) ? w : (nch - 1);
        const unsigned short* bp = bbase + (size_t)cc0 * (16 * EDIM);
        #pragma unroll
        for (int t = 0; t < 4; t++) bA[t] = *(const bf16x8*)(bp + t * 32);
    }
    for (int iter = 0; iter < NITER; iter += 2) {    // NITER even: no tail
        body(iter,     bA, bB);
        body(iter + 1, bB, bA);
    }

    // final compact guaranteed: survivors in [0,32) of each row
    for (int j = 0; j < 8; j++) {
        int b = (w << 3) + j;
        if (lane < NKEEP)
            candOut[(b0 + b) * NCAND + r * NKEEP + lane] =
                (int)cb[b * CAPR + lane].y;
    }
}

// ---------------- K3: fp64 rescore of 128 candidates, exact top-21 ----------
__global__ __launch_bounds__(256) void rescore(
        const int* __restrict__ seq, const int* __restrict__ len,
        const float* __restrict__ emb, const int* __restrict__ cand,
        float* __restrict__ out) {
    __shared__ double qd[EDIM];
    __shared__ double sv[NCAND];
    __shared__ int    si[NCAND];
    int b = blockIdx.x, t = threadIdx.x;
    int n = len[b];
    if (t < EDIM) {
        double s = 0.0;
        for (int l = 0; l < n; l++)
            s += (double)emb[(size_t)seq[b * HLEN + l] * EDIM + t];
        qd[t] = s / (double)(n > 0 ? n : 1);
    }
    __syncthreads();

    int c = t >> 1, h = t & 1;                       // 2 threads per candidate
    int idx = cand[b * NCAND + c];
    const float4* ev = (const float4*)(emb + (size_t)idx * EDIM + h * 64);
    double part = 0.0;
    #pragma unroll 4
    for (int j = 0; j < 16; j++) {
        float4 e = ev[j];
        int d = h * 64 + j * 4;
        part += qd[d] * (double)e.x + qd[d + 1] * (double)e.y
              + qd[d + 2] * (double)e.z + qd[d + 3] * (double)e.w;
    }
    part += __shfl_xor(part, 1);                     // combine halves
    if (h == 0) { sv[c] = part; si[c] = idx; }
    __syncthreads();

    if (t < NCAND) {                                 // rank among 128 (ties: low idx)
        double v = sv[t]; int id = si[t];
        int rank = 0;
        for (int j = 0; j < NCAND; j++) {
            double vj = sv[j]; int ij = si[j];
            rank += (vj > v || (vj == v && ij < id)) ? 1 : 0;
        }
        if (rank < TOPK) {
            out[(size_t)b * TOPK + rank] = (float)v;
            out[(size_t)BATCH * TOPK + (size_t)b * TOPK + rank] = (float)id;
        }
    }
}

extern "C" void kernel_launch(void* const* d_in, const int* in_sizes, int n_in,
                              void* d_out, int out_size, void* d_ws, size_t ws_size,
                              hipStream_t stream) {
    const int*   seq = (const int*)d_in[0];
    const int*   len = (const int*)d_in[1];
    const float* emb = (const float*)d_in[2];
    float* out = (float*)d_out;

    // ws layout: q_bf [4096*128 u16] | emb_bf [100000*128 u16] | cand [4096*128 i32]
    unsigned short* qbf  = (unsigned short*)d_ws;
    unsigned short* ebf  = qbf + (size_t)BATCH * EDIM;
    int*            cand = (int*)(ebf + (size_t)V_ITEMS * EDIM);

    conv_bf16 <<<(V_ITEMS * EDIM) / (256 * 8), 256, 0, stream>>>(emb, ebf);
    query_bf16<<<BATCH, EDIM, 0, stream>>>(seq, len, emb, qbf);
    score_topk<<<(BATCH / MT) * VSPLIT, 512, 0, stream>>>(qbf, ebf, cand);
    rescore   <<<BATCH, 256, 0, stream>>>(seq, len, emb, cand, out);
}